// Round 5
// baseline (490.961 us; speedup 1.0000x reference)
//
#include <hip/hip_runtime.h>

#define B_ 2
#define S_ 2048
#define D_ 1024
#define H_ 16
#define DH_ 64
#define DF_ 4096
#define M_ (B_*S_)   // 4096

typedef __bf16 bf16_t;
typedef __attribute__((ext_vector_type(4))) __bf16 bf16x4;
typedef __attribute__((ext_vector_type(8))) __bf16 bf16x8;
typedef __attribute__((ext_vector_type(4))) float f32x4;

__device__ inline f32x4 mfma16(bf16x8 a, bf16x8 b, f32x4 c){
  return __builtin_amdgcn_mfma_f32_16x16x32_bf16(a, b, c, 0, 0, 0);
}

__device__ inline void glds16(const void* g, void* l){
  __builtin_amdgcn_global_load_lds((const __attribute__((address_space(1))) void*)g,
                                   (__attribute__((address_space(3))) void*)l, 16, 0, 0);
}

// ---- repack Wq/Wk/Wv [H][D][DH] fp32 -> [N=h*DH+dh][K=d] bf16 ----
__global__ __launch_bounds__(256) void repack_qkv_k(const float* __restrict__ w,
                                                    bf16_t* __restrict__ o){
  int idx = blockIdx.x * 256 + threadIdx.x;     // over D_*D_
  int n = idx >> 10, d = idx & (D_ - 1);
  o[idx] = (bf16_t)w[((size_t)(n >> 6) * D_ + d) * DH_ + (n & 63)];
}

// ---- transpose fp32 [K][N] -> bf16 [N][K] ----
__global__ __launch_bounds__(256) void transpose_f2b_k(const float* __restrict__ in,
                                                       bf16_t* __restrict__ out,
                                                       int K, int N){
  __shared__ float t[32][33];
  int kb = blockIdx.x * 32, nb = blockIdx.y * 32;
  for (int i = threadIdx.y; i < 32; i += 8)
    t[i][threadIdx.x] = in[(size_t)(kb + i) * N + nb + threadIdx.x];
  __syncthreads();
  for (int i = threadIdx.y; i < 32; i += 8)
    out[(size_t)(nb + i) * K + kb + threadIdx.x] = (bf16_t)t[threadIdx.x][i];
}

// ---- LayerNorm fp32 row -> bf16 ----
__global__ __launch_bounds__(256) void ln_k(const float* __restrict__ x,
                                            const float* __restrict__ g,
                                            const float* __restrict__ o,
                                            bf16_t* __restrict__ out){
  int row = blockIdx.x;
  const float* xr = x + (size_t)row * D_;
  f32x4 v = *((const f32x4*)xr + threadIdx.x);
  float s  = v[0] + v[1] + v[2] + v[3];
  float sq = v[0]*v[0] + v[1]*v[1] + v[2]*v[2] + v[3]*v[3];
  #pragma unroll
  for (int off = 1; off < 64; off <<= 1){
    s  += __shfl_xor(s, off);
    sq += __shfl_xor(sq, off);
  }
  __shared__ float ss[4], ssq[4];
  int wid = threadIdx.x >> 6;
  if ((threadIdx.x & 63) == 0){ ss[wid] = s; ssq[wid] = sq; }
  __syncthreads();
  s  = ss[0] + ss[1] + ss[2] + ss[3];
  sq = ssq[0] + ssq[1] + ssq[2] + ssq[3];
  float mean = s * (1.0f / D_);
  float var  = fmaxf(sq * (1.0f / D_) - mean * mean, 0.0f);
  float inv  = 1.0f / (sqrtf(var) + 1e-9f);
  int c = threadIdx.x * 4;
  bf16_t* orow = out + (size_t)row * D_;
  #pragma unroll
  for (int j = 0; j < 4; j++)
    orow[c + j] = (bf16_t)(g[c + j] * ((v[j] - mean) * inv) + o[c + j]);
}

// ---- GEMM: C[M,N] = A[M,K](bf16) @ Bt[N,K](bf16)^T, global_load_lds staging ----
// EPI 0: fused QKV -> Q/K [bh][s][dh], V^T [bh][dh][s]   (outp = QKV base, bias = concat[3072])
// EPI 2: fp32 out = acc + bias + resid
// EPI 3: bf16 out = relu(acc + bias)
template<int EPI>
__global__ __launch_bounds__(256) void gemm_k(const bf16_t* __restrict__ A,
                                              const bf16_t* __restrict__ Bt,
                                              const float* __restrict__ bias,
                                              const float* __restrict__ resid,
                                              void* __restrict__ outp,
                                              int M, int N, int K){
  __shared__ bf16_t As[128][32];
  __shared__ bf16_t Bs[128][32];
  const int tid  = threadIdx.x;
  const int lane = tid & 63, wid = tid >> 6;
  const int m0 = blockIdx.x * 128, n0 = blockIdx.y * 128;
  const int wr = (wid >> 1) * 64, wc = (wid & 1) * 64;
  const int fr = lane & 15, kk = (lane >> 4) * 8;
  const int srow = tid >> 2, scol = (tid & 3) * 8;   // staging row / col (elements)
  f32x4 acc[4][4];
  #pragma unroll
  for (int m = 0; m < 4; m++)
    #pragma unroll
    for (int n = 0; n < 4; n++) acc[m][n] = (f32x4){0, 0, 0, 0};

  const bf16_t* Ag = A  + (size_t)(m0 + srow) * K + scol;
  const bf16_t* Bg = Bt + (size_t)(n0 + srow) * K + scol;
  char* ldsA = (char*)&As[0][0] + tid * 16;
  char* ldsB = (char*)&Bs[0][0] + tid * 16;

  for (int k0 = 0; k0 < K; k0 += 32){
    glds16(Ag + k0,                  ldsA);
    glds16(Ag + (size_t)64 * K + k0, ldsA + 4096);
    glds16(Bg + k0,                  ldsB);
    glds16(Bg + (size_t)64 * K + k0, ldsB + 4096);
    __syncthreads();
    bf16x8 af[4], bfv[4];
    #pragma unroll
    for (int m = 0; m < 4; m++) af[m]  = *(const bf16x8*)&As[wr + m*16 + fr][kk];
    #pragma unroll
    for (int n = 0; n < 4; n++) bfv[n] = *(const bf16x8*)&Bs[wc + n*16 + fr][kk];
    #pragma unroll
    for (int m = 0; m < 4; m++)
      #pragma unroll
      for (int n = 0; n < 4; n++)
        acc[m][n] = mfma16(af[m], bfv[n], acc[m][n]);
    __syncthreads();
  }

  #pragma unroll
  for (int m = 0; m < 4; m++){
    #pragma unroll
    for (int n = 0; n < 4; n++){
      #pragma unroll
      for (int r = 0; r < 4; r++){
        int row = m0 + wr + m*16 + (lane >> 4) * 4 + r;
        int col = n0 + wc + n*16 + fr;
        if constexpr (EPI == 0){
          int seg = col >> 10, c = col & 1023;
          int h = c >> 6, dh = c & 63;
          int b = row >> 11, sidx = row & (S_ - 1);
          float val = acc[m][n][r] + bias[col];
          bf16_t* base = (bf16_t*)outp + (size_t)seg * M_ * D_;
          if (seg < 2)
            base[(((size_t)b * H_ + h) * S_ + sidx) * DH_ + dh] = (bf16_t)val;
          else
            base[(((size_t)b * H_ + h) * DH_ + dh) * S_ + sidx] = (bf16_t)val;
        } else if constexpr (EPI == 2){
          float val = acc[m][n][r] + bias[col];
          ((float*)outp)[(size_t)row * N + col] = val + resid[(size_t)row * N + col];
        } else {
          float val = acc[m][n][r] + bias[col];
          ((bf16_t*)outp)[(size_t)row * N + col] = (bf16_t)fmaxf(val, 0.0f);
        }
      }
    }
  }
}

// ---- causal flash attention, swapped-QK^T, ONE WAVE PER BLOCK ----
// Q,K [bh][s][dh], Vt [bh][dh][s] -> attn [b][s][h*dh]
// R5: attn was latency-bound (MfmaUtil 2.9%, Occupancy 22%): 1024 blocks with
//     64:1 causal work skew left SIMDs starved. Now grid = (S/16, BH) = 4096
//     single-wave blocks; the whole grid is co-resident (16 waves/CU), so the
//     HW scheduler balances the triangle and 4 waves/SIMD hide each other's
//     serial QK->softmax->PV chains.
__global__ __launch_bounds__(64, 4) void attn_k(const bf16_t* __restrict__ Q,
                                                const bf16_t* __restrict__ Kb,
                                                const bf16_t* __restrict__ Vt,
                                                bf16_t* __restrict__ outp){
  __shared__ bf16_t plds[16][40];   // P tile [q=16][k_local=32] pad 40
  __shared__ bf16_t tlds[16][72];   // epilogue transpose [q=16][dh=64] pad 72
  const int lane = threadIdx.x & 63;
  const int bh = blockIdx.y;
  const int qb = gridDim.x - 1 - blockIdx.x;       // heavy tiles launch first
  const int q0 = qb * 16;
  const int l15 = lane & 15, g = lane >> 4, g8 = g * 8;
  const bf16_t* Qp = Q  + (size_t)bh * S_ * DH_;
  const bf16_t* Kp = Kb + (size_t)bh * S_ * DH_;
  const bf16_t* Vp = Vt + (size_t)bh * DH_ * S_;
  // Q as B-operand: col = l15 = q row, k-dim = dh
  bf16x8 qf0 = *(const bf16x8*)&Qp[(q0 + l15) * DH_ + g8];
  bf16x8 qf1 = *(const bf16x8*)&Qp[(q0 + l15) * DH_ + 32 + g8];
  f32x4 o[4];
  #pragma unroll
  for (int t = 0; t < 4; t++) o[t] = (f32x4){0, 0, 0, 0};
  float mrun = -1e30f, lrun = 0.0f;
  const int qrow = q0 + l15;                       // this lane's q row
  bf16_t* pw = &plds[0][0];

  for (int kv0 = 0; kv0 <= q0 + 15; kv0 += 32){
    // K as A-operand: row = l15 = k row, k-dim = dh
    bf16x8 kf00 = *(const bf16x8*)&Kp[(kv0 + l15) * DH_ + g8];
    bf16x8 kf01 = *(const bf16x8*)&Kp[(kv0 + l15) * DH_ + 32 + g8];
    bf16x8 kf10 = *(const bf16x8*)&Kp[(kv0 + 16 + l15) * DH_ + g8];
    bf16x8 kf11 = *(const bf16x8*)&Kp[(kv0 + 16 + l15) * DH_ + 32 + g8];
    f32x4 s0 = (f32x4){0,0,0,0}, s1 = (f32x4){0,0,0,0};
    s0 = mfma16(kf00, qf0, s0);
    s0 = mfma16(kf01, qf1, s0);
    s1 = mfma16(kf10, qf0, s1);
    s1 = mfma16(kf11, qf1, s1);
    // lane holds S^T: col=q (l15), row=k = kv0 + g*4 + r (+16 for s1)
    const int kb = kv0 + g * 4;
    float a[8];
    #pragma unroll
    for (int r = 0; r < 4; r++){
      a[r]     = (kb + r      <= qrow) ? s0[r] * 0.125f : -1e30f;
      a[4 + r] = (kb + 16 + r <= qrow) ? s1[r] * 0.125f : -1e30f;
    }
    float pm = fmaxf(fmaxf(fmaxf(a[0],a[1]), fmaxf(a[2],a[3])),
                     fmaxf(fmaxf(a[4],a[5]), fmaxf(a[6],a[7])));
    pm = fmaxf(pm, __shfl_xor(pm, 16));
    pm = fmaxf(pm, __shfl_xor(pm, 32));
    float mnew = fmaxf(mrun, pm);
    float scl = __expf(mrun - mnew);
    float e[8], rs = 0.0f;
    #pragma unroll
    for (int i = 0; i < 8; i++){ e[i] = __expf(a[i] - mnew); rs += e[i]; }
    rs += __shfl_xor(rs, 16);
    rs += __shfl_xor(rs, 32);
    lrun = lrun * scl + rs;
    mrun = mnew;
    #pragma unroll
    for (int t = 0; t < 4; t++) o[t] *= scl;
    // P -> LDS as [q][k_local] (pad 40): lane writes 2x bf16x4
    bf16x4 p0, p1;
    #pragma unroll
    for (int r = 0; r < 4; r++){ p0[r] = (bf16_t)e[r]; p1[r] = (bf16_t)e[4 + r]; }
    *(bf16x4*)&pw[l15 * 40 + g * 4]      = p0;
    *(bf16x4*)&pw[l15 * 40 + 16 + g * 4] = p1;
    // P^T as B-operand: col = l15 = q, k-dim = kv local
    bf16x8 pa = *(const bf16x8*)&pw[l15 * 40 + g8];
    #pragma unroll
    for (int t = 0; t < 4; t++){
      // V^T as A-operand: row = l15 = dh (tile t), k-dim = kv
      bf16x8 vf = *(const bf16x8*)&Vp[(t * 16 + l15) * S_ + kv0 + g8];
      o[t] = mfma16(vf, pa, o[t]);   // O^T: col=q (l15), row = dh local
    }
  }

  // epilogue: O^T -> O via LDS transpose, coalesced store
  float inv = 1.0f / lrun;
  bf16_t* tw = &tlds[0][0];                         // [16 q][72 dh-padded]
  #pragma unroll
  for (int t = 0; t < 4; t++){
    bf16x4 w;
    #pragma unroll
    for (int r = 0; r < 4; r++) w[r] = (bf16_t)(o[t][r] * inv);
    *(bf16x4*)&tw[l15 * 72 + t * 16 + g * 4] = w;
  }
  const int b = bh >> 4, h = bh & 15;
  const int rr = lane >> 3, cc = (lane & 7) * 8;
  bf16x8 r0 = *(const bf16x8*)&tw[rr * 72 + cc];
  bf16x8 r1 = *(const bf16x8*)&tw[(rr + 8) * 72 + cc];
  *(bf16x8*)&outp[((size_t)b * S_ + q0 + rr) * D_ + h * 64 + cc]     = r0;
  *(bf16x8*)&outp[((size_t)b * S_ + q0 + rr + 8) * D_ + h * 64 + cc] = r1;
}

extern "C" void kernel_launch(void* const* d_in, const int* in_sizes, int n_in,
                              void* d_out, int out_size, void* d_ws, size_t ws_size,
                              hipStream_t stream){
  (void)in_sizes; (void)n_in; (void)out_size; (void)ws_size;
  const float* X  = (const float*)d_in[0];
  // d_in[1] = attention_mask (always causal tril) — handled analytically
  const float* g1 = (const float*)d_in[2];
  const float* o1 = (const float*)d_in[3];
  const float* g2 = (const float*)d_in[4];
  const float* o2 = (const float*)d_in[5];
  const float* Wq = (const float*)d_in[6];
  const float* bq = (const float*)d_in[7];
  const float* Wk = (const float*)d_in[8];
  const float* bk = (const float*)d_in[9];
  const float* Wv = (const float*)d_in[10];
  const float* bv = (const float*)d_in[11];
  const float* W0 = (const float*)d_in[12];
  const float* b0 = (const float*)d_in[13];
  const float* W1 = (const float*)d_in[14];
  const float* b1 = (const float*)d_in[15];
  const float* W2 = (const float*)d_in[16];
  const float* b2 = (const float*)d_in[17];

  char* ws = (char*)d_ws;
  const size_t MB = 1024 * 1024;
  bf16_t* Xn1    = (bf16_t*)(ws + 0);        // 8MB; reused as attn out later
  bf16_t* attn   = (bf16_t*)(ws + 0);
  bf16_t* Wqkvt  = (bf16_t*)(ws + 8  * MB);  // 6MB  [3072][1024]
  bf16_t* W0t    = (bf16_t*)(ws + 14 * MB);  // 2MB
  bf16_t* W1t    = (bf16_t*)(ws + 16 * MB);  // 8MB
  bf16_t* W2t    = (bf16_t*)(ws + 24 * MB);  // 8MB
  bf16_t* QKV    = (bf16_t*)(ws + 32 * MB);  // 24MB: Q@32, K@40, V^T@48
  bf16_t* Qb     = QKV;
  bf16_t* Kbuf   = QKV + (size_t)M_ * D_;
  bf16_t* Vtb    = QKV + (size_t)2 * M_ * D_;
  bf16_t* hid    = (bf16_t*)(ws + 32 * MB);  // 32MB, reuses QKV after attention
  float*  qkvbias= (float*)(ws + 60 * MB);   // 12KB; dead before hid's region is written
  float*  X2     = (float*) (ws + 64 * MB);  // 16MB
  bf16_t* Xn2    = (bf16_t*)(ws + 80 * MB);  // 8MB  (total 88MB)

  dim3 b256(256);
  repack_qkv_k<<<dim3(D_*D_/256), b256, 0, stream>>>(Wq, Wqkvt);
  repack_qkv_k<<<dim3(D_*D_/256), b256, 0, stream>>>(Wk, Wqkvt + (size_t)D_*D_);
  repack_qkv_k<<<dim3(D_*D_/256), b256, 0, stream>>>(Wv, Wqkvt + (size_t)2*D_*D_);
  transpose_f2b_k<<<dim3(D_/32,  D_/32),  dim3(32,8), 0, stream>>>(W0, W0t, D_,  D_);
  transpose_f2b_k<<<dim3(D_/32,  DF_/32), dim3(32,8), 0, stream>>>(W1, W1t, D_,  DF_);
  transpose_f2b_k<<<dim3(DF_/32, D_/32),  dim3(32,8), 0, stream>>>(W2, W2t, DF_, D_);
  hipMemcpyAsync(qkvbias,        bq, D_*sizeof(float), hipMemcpyDeviceToDevice, stream);
  hipMemcpyAsync(qkvbias + D_,   bk, D_*sizeof(float), hipMemcpyDeviceToDevice, stream);
  hipMemcpyAsync(qkvbias + 2*D_, bv, D_*sizeof(float), hipMemcpyDeviceToDevice, stream);
  ln_k<<<dim3(M_), b256, 0, stream>>>(X, g1, o1, Xn1);
  gemm_k<0><<<dim3(M_/128, 3*D_/128), b256, 0, stream>>>(Xn1, Wqkvt, qkvbias, nullptr, QKV, M_, 3*D_, D_);
  attn_k<<<dim3(S_/16, B_*H_), dim3(64), 0, stream>>>(Qb, Kbuf, Vtb, attn);
  gemm_k<2><<<dim3(M_/128, D_/128),  b256, 0, stream>>>(attn, W0t, b0, X,  X2, M_, D_,  D_);
  ln_k<<<dim3(M_), b256, 0, stream>>>(X2, g2, o2, Xn2);
  gemm_k<3><<<dim3(M_/128, DF_/128), b256, 0, stream>>>(Xn2, W1t, b1, nullptr, hid, M_, DF_, D_);
  gemm_k<2><<<dim3(M_/128, D_/128),  b256, 0, stream>>>(hid, W2t, b2, X2, (float*)d_out, M_, D_, DF_);
}